// Round 17
// baseline (886.273 us; speedup 1.0000x reference)
//
#include <hip/hip_runtime.h>
#include <math.h>

#pragma clang fp contract(fast)

#define S    612
#define TT   8192
#define NB   32
#define SPW  256          // per-wave emission row width in floats (4 per lane)

typedef float v2f __attribute__((ext_vector_type(2)));

// workspace layout (bytes)
#define WIN_OFF   0        // 640 float4 = 10240
#define IV_OFF    10240    // 4 floats
#define EMIS_OFF  16384    // 4*100*256 floats = 409600 -> ends 425984
#define OBS_OFF   425984   // 32*8192 ints = 1 MB

// incoming-weight table: wIn2[t] = (in0,in1,in2,in3), in_k = row((t-k)%S)[k]
__global__ __launch_bounds__(256) void prep_tables(
    const float* __restrict__ tk, const float* __restrict__ ik,
    float* __restrict__ wIn2, float* __restrict__ Ivec)
{
    int i = blockIdx.x * 256 + threadIdx.x;
    if (i < S) {
        float l0 = tk[3*i], l1 = tk[3*i+1], l2 = tk[3*i+2], l3 = 1.0f;
        float m = fmaxf(fmaxf(l0, l1), fmaxf(l2, l3));
        float e0 = expf(l0-m), e1 = expf(l1-m), e2 = expf(l2-m), e3 = expf(l3-m);
        float inv = 1.0f / (e0+e1+e2+e3);
        wIn2[4*i + 0]              = e0*inv;
        wIn2[4*((i+1)%S) + 1]      = e1*inv;
        wIn2[4*((i+2)%S) + 2]      = e2*inv;
        wIn2[4*((i+3)%S) + 3]      = e3*inv;
    } else if (i < 640) {
        wIn2[4*i+0] = 0.f; wIn2[4*i+1] = 0.f; wIn2[4*i+2] = 0.f; wIn2[4*i+3] = 0.f;
    } else if (i == 640) {
        float l0 = ik[0], l1 = ik[1], l2 = ik[2], l3 = ik[3];
        float m = fmaxf(fmaxf(l0,l1), fmaxf(l2,l3));
        float e0 = expf(l0-m), e1 = expf(l1-m), e2 = expf(l2-m), e3 = expf(l3-m);
        float inv = 1.0f / (e0+e1+e2+e3);
        Ivec[0]=e0*inv; Ivec[1]=e1*inv; Ivec[2]=e2*inv; Ivec[3]=e3*inv;
    }
}

// per-wave emission tables; wave wv, row o, lane ln holds float4
// (E(pos0),E(pos2),E(pos1),E(pos3)) for local pos 4*ln+c,
// state s = (haloBase_wv + pos) % 612; zero for pads / state 611.
__global__ __launch_bounds__(256) void prep_emis4(
    const float* __restrict__ ek, float* __restrict__ emisP)
{
    int tid = blockIdx.x * 256 + threadIdx.x;
    if (tid >= 4*100*SPW) return;
    int wv = tid / (100*SPW);
    int r  = tid % (100*SPW);
    int o  = r / SPW;
    int q  = r % SPW;
    int ln = q >> 2, j = q & 3;
    int c = (j==0) ? 0 : (j==1) ? 2 : (j==2) ? 1 : 3;
    int pos = 4*ln + c;
    int haloBase = (wv==0) ? 564 : (wv==1) ? 104 : (wv==2) ? 256 : 408;
    int CWv = (wv==3) ? 204 : 200;
    float val = 0.0f;
    if (pos < CWv) {
        int s = (haloBase + pos) % S;
        if (s < S-1) {
            int ctx = o >> 2, le = o & 3;
            if (ctx == 0) {
                val = 0.25f;
            } else {
                const float* g = ek + s*96 + (ctx-1)*4;
                float a0=g[0], a1=g[1], a2=g[2], a3=g[3];
                float m = fmaxf(fmaxf(a0,a1), fmaxf(a2,a3));
                float x0=expf(a0-m), x1=expf(a1-m), x2=expf(a2-m), x3=expf(a3-m);
                float inv = 1.0f/(x0+x1+x2+x3);
                val = ((le==0)?x0:(le==1)?x1:(le==2)?x2:x3) * inv;
            }
        }
    }
    emisP[tid] = val;
}

__global__ __launch_bounds__(256) void extract_obs(
    const float* __restrict__ x, int* __restrict__ obs)
{
    int row  = blockIdx.x * 4 + (threadIdx.x >> 6);
    int lane = threadIdx.x & 63;
    if (row >= NB*TT) return;
    const float* r = x + (size_t)row * 101;
    float acc = r[lane] * (float)lane;
    if (lane < 37) acc += r[64 + lane] * (float)(64 + lane);
    #pragma unroll
    for (int m = 32; m >= 1; m >>= 1) acc += __shfl_xor(acc, m, 64);
    if (lane == 0) obs[row] = (int)(acc + 0.5f);
}

__device__ __forceinline__ float dpp_up1(float x) {
    int xi = __builtin_bit_cast(int, x);
    int r = __builtin_amdgcn_update_dpp(0, xi, 0x138, 0xF, 0xF, true);
    return __builtin_bit_cast(float, r);
}
template<int CTRL>
__device__ __forceinline__ float dpp_add(float x) {
    int sh = __builtin_amdgcn_update_dpp(0, __builtin_bit_cast(int, x), CTRL, 0xF, 0xF, true);
    return x + __builtin_bit_cast(float, sh);
}

// 2-pair core: p[0]=(pos0,pos2), p[1]=(pos1,pos3) per lane (stride-2 pairs).
// Lane 0's missing predecessors are DPP zeros -> garbage creeps into the
// 48-halo only (3 positions/step, 16 steps); no wrap patch needed.
#define CORE(E0,E1)                                                          \
  {                                                                          \
    float pm1 = dpp_up1(p[1].y);        /* pos 4l-1 */                       \
    float pm2 = dpp_up1(p[0].y);        /* pos 4l-2 */                       \
    float pm3 = dpp_up1(p[1].x);        /* pos 4l-3 */                       \
    v2f B1; B1.x = pm1; B1.y = p[1].x;                                       \
    v2f B2; B2.x = pm2; B2.y = p[0].x;                                       \
    v2f B3; B3.x = pm3; B3.y = pm1;                                          \
    v2f c0 = p[0]*W[0][0] + B1*W[0][1]   + B2*W[0][2] + B3*W[0][3];          \
    v2f c1 = p[1]*W[1][0] + p[0]*W[1][1] + B1*W[1][2] + B2*W[1][3];          \
    p[0] = c0*(E0); p[1] = c1*(E1);                                          \
  }

#define PFX(JB, OV)                                                          \
  { int _oo = __builtin_amdgcn_readfirstlane(OV);                            \
    float4 _q = *(const float4*)(ebase + _oo*SPW + 4*l);                     \
    eb[JB][0] = (v2f){_q.x,_q.y};                                            \
    eb[JB][1] = (v2f){_q.z,_q.w}; }

#define STEPX(JB, OV)  CORE(eb[JB][0],eb[JB][1]); PFX(JB, OV);

// boundary: masked z reduce, 4-wave ring halo exchange via LDS, global renorm
#define BOUNDARY()                                                           \
  { v2f _t = p[0] + p[1];                                                    \
    float zr = (_t.x + _t.y) * zmask;                                        \
    zr = dpp_add<0x111>(zr); zr = dpp_add<0x112>(zr);                        \
    zr = dpp_add<0x114>(zr); zr = dpp_add<0x118>(zr);                        \
    zr = dpp_add<0x142>(zr); zr = dpp_add<0x143>(zr);                        \
    if (l >= exBase && l < exBase + 12) {                                    \
      float* _o = &box[par][bat][wv][4*(l - exBase)];                        \
      _o[0]=p[0].x; _o[1]=p[1].x; _o[2]=p[0].y; _o[3]=p[1].y;                \
    }                                                                        \
    if (l == 63) box[par][bat][wv][48] = zr;                                 \
    __syncthreads();                                                         \
    if (l < 12) {                                                            \
      const float* _q = &box[par][bat][(wv+3)&3][4*l];                       \
      p[0].x=_q[0]; p[1].x=_q[1]; p[0].y=_q[2]; p[1].y=_q[3];                \
    }                                                                        \
    float z = ((box[par][bat][0][48] + box[par][bat][1][48]) +               \
               (box[par][bat][2][48] + box[par][bat][3][48]));               \
    float inv_ = __builtin_amdgcn_rcpf(z);                                   \
    ll += __logf(z);                                                         \
    v2f _iv; _iv.x = inv_; _iv.y = inv_;                                     \
    p[0] = p[0]*_iv; p[1] = p[1]*_iv;                                        \
    par ^= 1; }

// 8 waves per block = 2 batches x 4 sub-waves; 2 waves per SIMD fill each
// other's dependency bubbles (independent chains). 48 VGPR/wave -> no spill.
__global__ __launch_bounds__(512, 1) void forward(
    const float* __restrict__ emisP, const float4* __restrict__ wIn2,
    const float* __restrict__ Ivec, const int* __restrict__ obs,
    float* __restrict__ out)
{
    const int tid = threadIdx.x;
    const int l   = tid & 63;
    const int w8  = tid >> 6;      // 0..7
    const int bat = w8 >> 2;       // 0 or 1: which batch of this block
    const int wv  = w8 & 3;        // sub-wave within the batch's 4-way split
    const int b   = blockIdx.x * 2 + bat;
    const int* obp = obs + b * TT;
    const int haloBase = (wv==0) ? 564 : (wv==1) ? 104 : (wv==2) ? 256 : 408;
    const int owned    = (wv==3) ? 156 : 152;
    const int CWv      = owned + 48;
    const int exBase   = owned >> 2;            // 38 or 39
    const float* ebase = emisP + (size_t)wv * 100 * SPW;
    __shared__ float box[2][2][4][56];          // parity x batch x wave x padded row

    // per-lane weights: W[pair][k] = (in_k(pos 4l+pair), in_k(pos 4l+pair+2))
    v2f W[2][4];
    {
        float4 wq[4];
        #pragma unroll
        for (int c = 0; c < 4; ++c) {
            int pos = 4*l + c;
            if (pos < CWv) wq[c] = wIn2[(haloBase + pos) % S];
            else           wq[c] = make_float4(0.f, 0.f, 0.f, 0.f);
        }
        W[0][0].x = wq[0].x;  W[0][0].y = wq[2].x;
        W[0][1].x = wq[0].y;  W[0][1].y = wq[2].y;
        W[0][2].x = wq[0].z;  W[0][2].y = wq[2].z;
        W[0][3].x = wq[0].w;  W[0][3].y = wq[2].w;
        W[1][0].x = wq[1].x;  W[1][0].y = wq[3].x;
        W[1][1].x = wq[1].y;  W[1][1].y = wq[3].y;
        W[1][2].x = wq[1].z;  W[1][2].y = wq[3].z;
        W[1][3].x = wq[1].w;  W[1][3].y = wq[3].w;
    }
    const float zmask = (l >= 12 && l <= ((wv==3) ? 50 : 49)) ? 1.0f : 0.0f;

    // obs blocks (uniform scalar regs)
    int4 q0, a1, a2, a3, b0, b1, b2, b3;
    {
        const int4* o4 = (const int4*)obp;
        q0 = o4[0]; a1 = o4[1]; a2 = o4[2]; a3 = o4[3];
        b0 = o4[4]; b1 = o4[5]; b2 = o4[6]; b3 = o4[7];
    }

    v2f p[2];
    p[0] = (v2f){0.f,0.f}; p[1] = (v2f){0.f,0.f};
    float ll = 0.0f;
    v2f eb[4][2];
    int par = 0;

    // t = 0: states 0..3 live at wave0 local pos 48..51 (lane 12)
    {
        int o0 = __builtin_amdgcn_readfirstlane(q0.x);
        float4 q = *(const float4*)(ebase + o0*SPW + 4*l);
        if (wv == 0 && l == 12) {
            p[0].x = q.x * Ivec[0];   // state 0 (pos 48)
            p[0].y = q.y * Ivec[2];   // state 2 (pos 50)
            p[1].x = q.z * Ivec[1];   // state 1 (pos 49)
            p[1].y = q.w * Ivec[3];   // state 3 (pos 51)
        }
    }

    BOUNDARY();   // t=0: z0, log, renorm, (zero) halo import

    // initial emission buffers for steps 1..4 (ids 1,2,3,0)
    PFX(1, q0.y); PFX(2, q0.z); PFX(3, q0.w); PFX(0, a1.x);

    // windows g = 0..510: steps 16g+1 .. 16g+16, boundary after each
    #pragma unroll 1
    for (int g = 0; g < 511; ++g) {
        STEPX(1, a1.y); STEPX(2, a1.z); STEPX(3, a1.w); STEPX(0, a2.x);
        STEPX(1, a2.y); STEPX(2, a2.z); STEPX(3, a2.w); STEPX(0, a3.x);
        STEPX(1, a3.y); STEPX(2, a3.z); STEPX(3, a3.w); STEPX(0, b0.x);
        STEPX(1, b0.y); STEPX(2, b0.z); STEPX(3, b0.w); STEPX(0, b1.x);
        BOUNDARY();
        a1 = b1; a2 = b2; a3 = b3;
        int off = 16*(g+2); if (off > TT-16) off = TT-16;
        const int4* o4 = (const int4*)(obp + off);
        b0 = o4[0]; b1 = o4[1]; b2 = o4[2]; b3 = o4[3];
    }

    // final partial window: steps 8177..8191 (15 steps)
    STEPX(1, a1.y); STEPX(2, a1.z); STEPX(3, a1.w); STEPX(0, a2.x);
    STEPX(1, a2.y); STEPX(2, a2.z); STEPX(3, a2.w); STEPX(0, a3.x);
    STEPX(1, a3.y); STEPX(2, a3.z); STEPX(3, a3.w); STEPX(0, b0.x);
    STEPX(1, b0.y); STEPX(2, b0.z); STEPX(3, b0.w);

    // final z (cross-wave, per batch)
    {
        v2f t = p[0] + p[1];
        float zr = (t.x + t.y) * zmask;
        zr = dpp_add<0x111>(zr); zr = dpp_add<0x112>(zr);
        zr = dpp_add<0x114>(zr); zr = dpp_add<0x118>(zr);
        zr = dpp_add<0x142>(zr); zr = dpp_add<0x143>(zr);
        if (l == 63) box[par][bat][wv][48] = zr;
        __syncthreads();
        float z = ((box[par][bat][0][48] + box[par][bat][1][48]) +
                   (box[par][bat][2][48] + box[par][bat][3][48]));
        ll += __logf(z);
    }
    if (wv == 0 && l == 0) out[b] = ll;
}

extern "C" void kernel_launch(void* const* d_in, const int* in_sizes, int n_in,
                              void* d_out, int out_size, void* d_ws, size_t ws_size,
                              hipStream_t stream)
{
    const float* x  = (const float*)d_in[0];   // inputs [32,8192,101]
    const float* ik = (const float*)d_in[1];   // init_kernel [4]
    const float* tk = (const float*)d_in[2];   // transition_kernel [1836]
    const float* ek = (const float*)d_in[3];   // emission_kernel [58656]
    float* out = (float*)d_out;

    char* ws = (char*)d_ws;
    float*  wIn2  = (float*)(ws + WIN_OFF);
    float*  Ivec  = (float*)(ws + IV_OFF);
    float*  emisP = (float*)(ws + EMIS_OFF);
    int*    obs   = (int*)(ws + OBS_OFF);

    hipLaunchKernelGGL(prep_tables, dim3(3), dim3(256), 0, stream, tk, ik, wIn2, Ivec);
    hipLaunchKernelGGL(prep_emis4, dim3((4*100*SPW + 255)/256), dim3(256), 0, stream,
                       ek, emisP);
    hipLaunchKernelGGL(extract_obs, dim3((NB*TT + 3)/4), dim3(256), 0, stream, x, obs);
    hipLaunchKernelGGL(forward, dim3(NB/2), dim3(512), 0, stream,
                       emisP, (const float4*)wIn2, Ivec, obs, out);
}

// Round 18
// 783.244 us; speedup vs baseline: 1.1315x; 1.1315x over previous
//
#include <hip/hip_runtime.h>
#include <math.h>

#pragma clang fp contract(fast)

#define S     612
#define TT    8192
#define NB    32
#define SPW8  128         // per-wave emission row width in floats (2 per lane)

typedef float v2f __attribute__((ext_vector_type(2)));

// workspace layout (bytes)
#define WIN_OFF   0        // 640 float4 = 10240
#define IV_OFF    10240    // 4 floats
#define EMIS_OFF  16384    // 8*100*128 floats = 409600 -> ends 425984
#define OBS_OFF   425984   // 32*8192 ints = 1 MB

__device__ __host__ __forceinline__ int wave_own(int wv)  { return 76 + ((wv >= 6) ? 2 : 0); }
__device__ __host__ __forceinline__ int wave_O(int wv)    { return 76*wv + ((wv >= 7) ? 2 : 0); }
__device__ __host__ __forceinline__ int wave_halo(int wv) { return (wave_O(wv) + S - 48) % S; }

// incoming-weight table: wIn2[t] = (in0,in1,in2,in3), in_k = row((t-k)%S)[k]
__global__ __launch_bounds__(256) void prep_tables(
    const float* __restrict__ tk, const float* __restrict__ ik,
    float* __restrict__ wIn2, float* __restrict__ Ivec)
{
    int i = blockIdx.x * 256 + threadIdx.x;
    if (i < S) {
        float l0 = tk[3*i], l1 = tk[3*i+1], l2 = tk[3*i+2], l3 = 1.0f;
        float m = fmaxf(fmaxf(l0, l1), fmaxf(l2, l3));
        float e0 = expf(l0-m), e1 = expf(l1-m), e2 = expf(l2-m), e3 = expf(l3-m);
        float inv = 1.0f / (e0+e1+e2+e3);
        wIn2[4*i + 0]              = e0*inv;
        wIn2[4*((i+1)%S) + 1]      = e1*inv;
        wIn2[4*((i+2)%S) + 2]      = e2*inv;
        wIn2[4*((i+3)%S) + 3]      = e3*inv;
    } else if (i < 640) {
        wIn2[4*i+0] = 0.f; wIn2[4*i+1] = 0.f; wIn2[4*i+2] = 0.f; wIn2[4*i+3] = 0.f;
    } else if (i == 640) {
        float l0 = ik[0], l1 = ik[1], l2 = ik[2], l3 = ik[3];
        float m = fmaxf(fmaxf(l0,l1), fmaxf(l2,l3));
        float e0 = expf(l0-m), e1 = expf(l1-m), e2 = expf(l2-m), e3 = expf(l3-m);
        float inv = 1.0f / (e0+e1+e2+e3);
        Ivec[0]=e0*inv; Ivec[1]=e1*inv; Ivec[2]=e2*inv; Ivec[3]=e3*inv;
    }
}

// per-wave emission tables; wave wv, row o, float index q (=local pos):
// state s = (haloBase_wv + q) % 612; zero beyond computed width / state 611.
__global__ __launch_bounds__(256) void prep_emis8(
    const float* __restrict__ ek, float* __restrict__ emisP)
{
    int tid = blockIdx.x * 256 + threadIdx.x;
    if (tid >= 8*100*SPW8) return;
    int wv = tid / (100*SPW8);
    int r  = tid % (100*SPW8);
    int o  = r / SPW8;
    int q  = r % SPW8;
    int CWv = wave_own(wv) + 48;
    float val = 0.0f;
    if (q < CWv) {
        int s = (wave_halo(wv) + q) % S;
        if (s < S-1) {
            int ctx = o >> 2, le = o & 3;
            if (ctx == 0) {
                val = 0.25f;
            } else {
                const float* g = ek + s*96 + (ctx-1)*4;
                float a0=g[0], a1=g[1], a2=g[2], a3=g[3];
                float m = fmaxf(fmaxf(a0,a1), fmaxf(a2,a3));
                float x0=expf(a0-m), x1=expf(a1-m), x2=expf(a2-m), x3=expf(a3-m);
                float inv = 1.0f/(x0+x1+x2+x3);
                val = ((le==0)?x0:(le==1)?x1:(le==2)?x2:x3) * inv;
            }
        }
    }
    emisP[tid] = val;
}

__global__ __launch_bounds__(256) void extract_obs(
    const float* __restrict__ x, int* __restrict__ obs)
{
    int row  = blockIdx.x * 4 + (threadIdx.x >> 6);
    int lane = threadIdx.x & 63;
    if (row >= NB*TT) return;
    const float* r = x + (size_t)row * 101;
    float acc = r[lane] * (float)lane;
    if (lane < 37) acc += r[64 + lane] * (float)(64 + lane);
    #pragma unroll
    for (int m = 32; m >= 1; m >>= 1) acc += __shfl_xor(acc, m, 64);
    if (lane == 0) obs[row] = (int)(acc + 0.5f);
}

__device__ __forceinline__ float dpp_up1(float x) {
    int xi = __builtin_bit_cast(int, x);
    int r = __builtin_amdgcn_update_dpp(0, xi, 0x138, 0xF, 0xF, true);
    return __builtin_bit_cast(float, r);
}
template<int CTRL>
__device__ __forceinline__ float dpp_add(float x) {
    int sh = __builtin_amdgcn_update_dpp(0, __builtin_bit_cast(int, x), CTRL, 0xF, 0xF, true);
    return x + __builtin_bit_cast(float, sh);
}

// 1-pair core: p = (a_{2l}, a_{2l+1}); shifts via DPP (d3 = double shift).
// Lane-0 zeros creep 3 positions/step -> contamination stays inside the
// 48-position halo over a 16-step window.
#define CORE1(E)                                                             \
  {                                                                          \
    float d1 = dpp_up1(p.y);            /* a_{2l-1} */                       \
    float d2 = dpp_up1(p.x);            /* a_{2l-2} */                       \
    float d3 = dpp_up1(d1);             /* a_{2l-3} */                       \
    v2f s1; s1.x = d1; s1.y = p.x;                                           \
    v2f s2; s2.x = d2; s2.y = d1;                                            \
    v2f s3; s3.x = d3; s3.y = d2;                                            \
    v2f c = p*W[0] + s1*W[1] + s2*W[2] + s3*W[3];                            \
    p = c*(E);                                                               \
  }

#define PFX(JB, OV)                                                          \
  { int _oo = __builtin_amdgcn_readfirstlane(OV);                            \
    float2 _q = *(const float2*)(ebase + _oo*SPW8 + 2*l);                    \
    eb[JB] = (v2f){_q.x,_q.y}; }

#define STEPX(JB, OV)  CORE1(eb[JB]); PFX(JB, OV);

// boundary: masked z reduce, 8-wave ring halo exchange via LDS, global renorm
#define BOUNDARY()                                                           \
  { float zr = (p.x + p.y) * zmask;                                          \
    zr = dpp_add<0x111>(zr); zr = dpp_add<0x112>(zr);                        \
    zr = dpp_add<0x114>(zr); zr = dpp_add<0x118>(zr);                        \
    zr = dpp_add<0x142>(zr); zr = dpp_add<0x143>(zr);                        \
    if (l >= exL && l < exL + 24) {                                          \
      float* _o = &box[par][wv][2*(l - exL)];                                \
      _o[0] = p.x; _o[1] = p.y;                                              \
    }                                                                        \
    if (l == 63) box[par][wv][48] = zr;                                      \
    __syncthreads();                                                         \
    if (l < 24) {                                                            \
      const float* _q = &box[par][(wv+7)&7][2*l];                            \
      p.x = _q[0]; p.y = _q[1];                                              \
    }                                                                        \
    float z = ((box[par][0][48] + box[par][1][48]) +                         \
               (box[par][2][48] + box[par][3][48])) +                        \
              ((box[par][4][48] + box[par][5][48]) +                         \
               (box[par][6][48] + box[par][7][48]));                         \
    float inv_ = __builtin_amdgcn_rcpf(z);                                   \
    ll += __logf(z);                                                         \
    v2f _iv; _iv.x = inv_; _iv.y = inv_;                                     \
    p = p*_iv;                                                               \
    par ^= 1; }

// 8 waves per block (2 per SIMD), 1 batch per block; wave wv owns 76/78
// states + 48 halo, 2 positions per lane.
__global__ __launch_bounds__(512, 1) void forward(
    const float* __restrict__ emisP, const float4* __restrict__ wIn2,
    const float* __restrict__ Ivec, const int* __restrict__ obs,
    float* __restrict__ out)
{
    const int tid = threadIdx.x;
    const int l   = tid & 63;
    const int wv  = tid >> 6;      // 0..7
    const int b   = blockIdx.x;
    const int* obp = obs + b * TT;
    const int own      = wave_own(wv);
    const int haloBase = wave_halo(wv);
    const int CWv      = own + 48;
    const int exL      = own >> 1;              // 38 or 39
    const float* ebase = emisP + (size_t)wv * 100 * SPW8;
    __shared__ float box[2][8][56];             // parity x wave x padded row

    // per-lane weights: W[k] = (in_k(pos 2l), in_k(pos 2l+1))
    v2f W[4];
    {
        float4 wq[2];
        #pragma unroll
        for (int c = 0; c < 2; ++c) {
            int pos = 2*l + c;
            if (pos < CWv) wq[c] = wIn2[(haloBase + pos) % S];
            else           wq[c] = make_float4(0.f, 0.f, 0.f, 0.f);
        }
        W[0].x = wq[0].x;  W[0].y = wq[1].x;
        W[1].x = wq[0].y;  W[1].y = wq[1].y;
        W[2].x = wq[0].z;  W[2].y = wq[1].z;
        W[3].x = wq[0].w;  W[3].y = wq[1].w;
    }
    const float zmask = (l >= 24 && l < 24 + (own >> 1)) ? 1.0f : 0.0f;

    // obs blocks (uniform scalar regs)
    int4 q0, a1, a2, a3, b0, b1, b2, b3;
    {
        const int4* o4 = (const int4*)obp;
        q0 = o4[0]; a1 = o4[1]; a2 = o4[2]; a3 = o4[3];
        b0 = o4[4]; b1 = o4[5]; b2 = o4[6]; b3 = o4[7];
    }

    v2f p;
    p.x = 0.f; p.y = 0.f;
    float ll = 0.0f;
    v2f eb[4];
    int par = 0;

    // t = 0: states 0..3 at wave0 local pos 48..51 (lanes 24,25)
    {
        int o0 = __builtin_amdgcn_readfirstlane(q0.x);
        float2 e = *(const float2*)(ebase + o0*SPW8 + 2*l);
        if (wv == 0) {
            if (l == 24) { p.x = e.x * Ivec[0]; p.y = e.y * Ivec[1]; }
            if (l == 25) { p.x = e.x * Ivec[2]; p.y = e.y * Ivec[3]; }
        }
    }

    BOUNDARY();   // t=0: z0, log, renorm, (zero) halo import

    // initial emission buffers for steps 1..4 (ids 1,2,3,0)
    PFX(1, q0.y); PFX(2, q0.z); PFX(3, q0.w); PFX(0, a1.x);

    // windows g = 0..510: steps 16g+1 .. 16g+16, boundary after each
    #pragma unroll 1
    for (int g = 0; g < 511; ++g) {
        STEPX(1, a1.y); STEPX(2, a1.z); STEPX(3, a1.w); STEPX(0, a2.x);
        STEPX(1, a2.y); STEPX(2, a2.z); STEPX(3, a2.w); STEPX(0, a3.x);
        STEPX(1, a3.y); STEPX(2, a3.z); STEPX(3, a3.w); STEPX(0, b0.x);
        STEPX(1, b0.y); STEPX(2, b0.z); STEPX(3, b0.w); STEPX(0, b1.x);
        BOUNDARY();
        a1 = b1; a2 = b2; a3 = b3;
        int off = 16*(g+2); if (off > TT-16) off = TT-16;
        const int4* o4 = (const int4*)(obp + off);
        b0 = o4[0]; b1 = o4[1]; b2 = o4[2]; b3 = o4[3];
    }

    // final partial window: steps 8177..8191 (15 steps)
    STEPX(1, a1.y); STEPX(2, a1.z); STEPX(3, a1.w); STEPX(0, a2.x);
    STEPX(1, a2.y); STEPX(2, a2.z); STEPX(3, a2.w); STEPX(0, a3.x);
    STEPX(1, a3.y); STEPX(2, a3.z); STEPX(3, a3.w); STEPX(0, b0.x);
    STEPX(1, b0.y); STEPX(2, b0.z); STEPX(3, b0.w);

    // final z (cross-wave)
    {
        float zr = (p.x + p.y) * zmask;
        zr = dpp_add<0x111>(zr); zr = dpp_add<0x112>(zr);
        zr = dpp_add<0x114>(zr); zr = dpp_add<0x118>(zr);
        zr = dpp_add<0x142>(zr); zr = dpp_add<0x143>(zr);
        if (l == 63) box[par][wv][48] = zr;
        __syncthreads();
        float z = ((box[par][0][48] + box[par][1][48]) +
                   (box[par][2][48] + box[par][3][48])) +
                  ((box[par][4][48] + box[par][5][48]) +
                   (box[par][6][48] + box[par][7][48]));
        ll += __logf(z);
    }
    if (tid == 0) out[b] = ll;
}

extern "C" void kernel_launch(void* const* d_in, const int* in_sizes, int n_in,
                              void* d_out, int out_size, void* d_ws, size_t ws_size,
                              hipStream_t stream)
{
    const float* x  = (const float*)d_in[0];   // inputs [32,8192,101]
    const float* ik = (const float*)d_in[1];   // init_kernel [4]
    const float* tk = (const float*)d_in[2];   // transition_kernel [1836]
    const float* ek = (const float*)d_in[3];   // emission_kernel [58656]
    float* out = (float*)d_out;

    char* ws = (char*)d_ws;
    float*  wIn2  = (float*)(ws + WIN_OFF);
    float*  Ivec  = (float*)(ws + IV_OFF);
    float*  emisP = (float*)(ws + EMIS_OFF);
    int*    obs   = (int*)(ws + OBS_OFF);

    hipLaunchKernelGGL(prep_tables, dim3(3), dim3(256), 0, stream, tk, ik, wIn2, Ivec);
    hipLaunchKernelGGL(prep_emis8, dim3((8*100*SPW8 + 255)/256), dim3(256), 0, stream,
                       ek, emisP);
    hipLaunchKernelGGL(extract_obs, dim3((NB*TT + 3)/4), dim3(256), 0, stream, x, obs);
    hipLaunchKernelGGL(forward, dim3(NB), dim3(512), 0, stream,
                       emisP, (const float4*)wIn2, Ivec, obs, out);
}

// Round 19
// 514.896 us; speedup vs baseline: 1.7213x; 1.5212x over previous
//
#include <hip/hip_runtime.h>
#include <math.h>

#pragma clang fp contract(fast)

#define S    612
#define TT   8192
#define NB   32
#define SPW  256          // per-wave emission row width in floats (4 per lane)

typedef float v2f __attribute__((ext_vector_type(2)));

// workspace layout (bytes)
#define WIN_OFF   0        // 640 float4 = 10240
#define IV_OFF    10240    // 4 floats
#define EMIS_OFF  16384    // 4*100*256 floats = 409600 -> ends 425984
#define OBS_OFF   425984   // 32*8192 ints = 1 MB

// incoming-weight table: wIn2[t] = (in0,in1,in2,in3), in_k = row((t-k)%S)[k]
__global__ __launch_bounds__(256) void prep_tables(
    const float* __restrict__ tk, const float* __restrict__ ik,
    float* __restrict__ wIn2, float* __restrict__ Ivec)
{
    int i = blockIdx.x * 256 + threadIdx.x;
    if (i < S) {
        float l0 = tk[3*i], l1 = tk[3*i+1], l2 = tk[3*i+2], l3 = 1.0f;
        float m = fmaxf(fmaxf(l0, l1), fmaxf(l2, l3));
        float e0 = expf(l0-m), e1 = expf(l1-m), e2 = expf(l2-m), e3 = expf(l3-m);
        float inv = 1.0f / (e0+e1+e2+e3);
        wIn2[4*i + 0]              = e0*inv;
        wIn2[4*((i+1)%S) + 1]      = e1*inv;
        wIn2[4*((i+2)%S) + 2]      = e2*inv;
        wIn2[4*((i+3)%S) + 3]      = e3*inv;
    } else if (i < 640) {
        wIn2[4*i+0] = 0.f; wIn2[4*i+1] = 0.f; wIn2[4*i+2] = 0.f; wIn2[4*i+3] = 0.f;
    } else if (i == 640) {
        float l0 = ik[0], l1 = ik[1], l2 = ik[2], l3 = ik[3];
        float m = fmaxf(fmaxf(l0,l1), fmaxf(l2,l3));
        float e0 = expf(l0-m), e1 = expf(l1-m), e2 = expf(l2-m), e3 = expf(l3-m);
        float inv = 1.0f / (e0+e1+e2+e3);
        Ivec[0]=e0*inv; Ivec[1]=e1*inv; Ivec[2]=e2*inv; Ivec[3]=e3*inv;
    }
}

// per-wave emission tables; wave wv, row o, lane ln holds float4
// (E(pos0),E(pos2),E(pos1),E(pos3)) for local pos 4*ln+c,
// state s = (haloBase_wv + pos) % 612; zero for pads / state 611.
// halo = 96 positions; owned = 152 (wv 0..2) / 156 (wv 3).
__global__ __launch_bounds__(256) void prep_emis4(
    const float* __restrict__ ek, float* __restrict__ emisP)
{
    int tid = blockIdx.x * 256 + threadIdx.x;
    if (tid >= 4*100*SPW) return;
    int wv = tid / (100*SPW);
    int r  = tid % (100*SPW);
    int o  = r / SPW;
    int q  = r % SPW;
    int ln = q >> 2, j = q & 3;
    int c = (j==0) ? 0 : (j==1) ? 2 : (j==2) ? 1 : 3;
    int pos = 4*ln + c;
    int haloBase = (wv==0) ? 516 : (wv==1) ? 56 : (wv==2) ? 208 : 360;
    int CWv = (wv==3) ? 252 : 248;
    float val = 0.0f;
    if (pos < CWv) {
        int s = (haloBase + pos) % S;
        if (s < S-1) {
            int ctx = o >> 2, le = o & 3;
            if (ctx == 0) {
                val = 0.25f;
            } else {
                const float* g = ek + s*96 + (ctx-1)*4;
                float a0=g[0], a1=g[1], a2=g[2], a3=g[3];
                float m = fmaxf(fmaxf(a0,a1), fmaxf(a2,a3));
                float x0=expf(a0-m), x1=expf(a1-m), x2=expf(a2-m), x3=expf(a3-m);
                float inv = 1.0f/(x0+x1+x2+x3);
                val = ((le==0)?x0:(le==1)?x1:(le==2)?x2:x3) * inv;
            }
        }
    }
    emisP[tid] = val;
}

__global__ __launch_bounds__(256) void extract_obs(
    const float* __restrict__ x, int* __restrict__ obs)
{
    int row  = blockIdx.x * 4 + (threadIdx.x >> 6);
    int lane = threadIdx.x & 63;
    if (row >= NB*TT) return;
    const float* r = x + (size_t)row * 101;
    float acc = r[lane] * (float)lane;
    if (lane < 37) acc += r[64 + lane] * (float)(64 + lane);
    #pragma unroll
    for (int m = 32; m >= 1; m >>= 1) acc += __shfl_xor(acc, m, 64);
    if (lane == 0) obs[row] = (int)(acc + 0.5f);
}

__device__ __forceinline__ float dpp_up1(float x) {
    int xi = __builtin_bit_cast(int, x);
    int r = __builtin_amdgcn_update_dpp(0, xi, 0x138, 0xF, 0xF, true);
    return __builtin_bit_cast(float, r);
}
template<int CTRL>
__device__ __forceinline__ float dpp_add(float x) {
    int sh = __builtin_amdgcn_update_dpp(0, __builtin_bit_cast(int, x), CTRL, 0xF, 0xF, true);
    return x + __builtin_bit_cast(float, sh);
}

// 2-pair core: p[0]=(pos0,pos2), p[1]=(pos1,pos3) per lane (stride-2 pairs).
// Lane 0's missing predecessors are DPP zeros -> garbage creeps into the
// 96-halo only (3 positions/step, 32 steps); no wrap patch needed.
#define CORE(E0,E1)                                                          \
  {                                                                          \
    float pm1 = dpp_up1(p[1].y);        /* pos 4l-1 */                       \
    float pm2 = dpp_up1(p[0].y);        /* pos 4l-2 */                       \
    float pm3 = dpp_up1(p[1].x);        /* pos 4l-3 */                       \
    v2f B1; B1.x = pm1; B1.y = p[1].x;                                       \
    v2f B2; B2.x = pm2; B2.y = p[0].x;                                       \
    v2f B3; B3.x = pm3; B3.y = pm1;                                          \
    v2f c0 = p[0]*W[0][0] + B1*W[0][1]   + B2*W[0][2] + B3*W[0][3];          \
    v2f c1 = p[1]*W[1][0] + p[0]*W[1][1] + B1*W[1][2] + B2*W[1][3];          \
    p[0] = c0*(E0); p[1] = c1*(E1);                                          \
  }

#define PFX(JB, OV)                                                          \
  { int _oo = __builtin_amdgcn_readfirstlane(OV);                            \
    float4 _q = *(const float4*)(ebase + _oo*SPW + 4*l);                     \
    eb[JB][0] = (v2f){_q.x,_q.y};                                            \
    eb[JB][1] = (v2f){_q.z,_q.w}; }

#define STEPX(JB, OV)  CORE(eb[JB][0],eb[JB][1]); PFX(JB, OV);
#define STEPC(JB)      CORE(eb[JB][0],eb[JB][1]);

// boundary: masked z reduce, 4-wave ring halo exchange (96 states) via LDS,
// global renorm. Rows padded to 104 floats (no power-of-2 bank stride).
#define BOUNDARY()                                                           \
  { v2f _t = p[0] + p[1];                                                    \
    float zr = (_t.x + _t.y) * zmask;                                        \
    zr = dpp_add<0x111>(zr); zr = dpp_add<0x112>(zr);                        \
    zr = dpp_add<0x114>(zr); zr = dpp_add<0x118>(zr);                        \
    zr = dpp_add<0x142>(zr); zr = dpp_add<0x143>(zr);                        \
    if (l >= exBase && l < exBase + 24) {                                    \
      float* _o = &box[par][wv][4*(l - exBase)];                             \
      _o[0]=p[0].x; _o[1]=p[1].x; _o[2]=p[0].y; _o[3]=p[1].y;                \
    }                                                                        \
    if (l == 63) box[par][wv][96] = zr;                                      \
    __syncthreads();                                                         \
    if (l < 24) {                                                            \
      const float* _q = &box[par][(wv+3)&3][4*l];                            \
      p[0].x=_q[0]; p[1].x=_q[1]; p[0].y=_q[2]; p[1].y=_q[3];                \
    }                                                                        \
    float z = ((box[par][0][96] + box[par][1][96]) +                         \
               (box[par][2][96] + box[par][3][96]));                         \
    float inv_ = __builtin_amdgcn_rcpf(z);                                   \
    ll += __logf(z);                                                         \
    v2f _iv; _iv.x = inv_; _iv.y = inv_;                                     \
    p[0] = p[0]*_iv; p[1] = p[1]*_iv;                                        \
    par ^= 1; }

// 4 waves per block, 1 batch per block; wave wv owns 152/156 states + 96 halo;
// 32-step windows between boundaries.
__global__ __launch_bounds__(256, 1) void forward(
    const float* __restrict__ emisP, const float4* __restrict__ wIn2,
    const float* __restrict__ Ivec, const int* __restrict__ obs,
    float* __restrict__ out)
{
    const int tid = threadIdx.x;
    const int l   = tid & 63;
    const int wv  = tid >> 6;
    const int b   = blockIdx.x;
    const int* obp = obs + b * TT;
    const int haloBase = (wv==0) ? 516 : (wv==1) ? 56 : (wv==2) ? 208 : 360;
    const int owned    = (wv==3) ? 156 : 152;
    const int CWv      = owned + 96;
    const int exBase   = owned >> 2;            // 38 or 39
    const float* ebase = emisP + (size_t)wv * 100 * SPW;
    __shared__ float box[2][4][104];            // parity x wave x padded row

    // per-lane weights: W[pair][k] = (in_k(pos 4l+pair), in_k(pos 4l+pair+2))
    v2f W[2][4];
    {
        float4 wq[4];
        #pragma unroll
        for (int c = 0; c < 4; ++c) {
            int pos = 4*l + c;
            if (pos < CWv) wq[c] = wIn2[(haloBase + pos) % S];
            else           wq[c] = make_float4(0.f, 0.f, 0.f, 0.f);
        }
        W[0][0].x = wq[0].x;  W[0][0].y = wq[2].x;
        W[0][1].x = wq[0].y;  W[0][1].y = wq[2].y;
        W[0][2].x = wq[0].z;  W[0][2].y = wq[2].z;
        W[0][3].x = wq[0].w;  W[0][3].y = wq[2].w;
        W[1][0].x = wq[1].x;  W[1][0].y = wq[3].x;
        W[1][1].x = wq[1].y;  W[1][1].y = wq[3].y;
        W[1][2].x = wq[1].z;  W[1][2].y = wq[3].z;
        W[1][3].x = wq[1].w;  W[1][3].y = wq[3].w;
    }
    const float zmask = (l >= 24 && l < 24 + (owned >> 2)) ? 1.0f : 0.0f;

    // obs blocks (uniform scalar regs): a* = obs[32g..32g+31], b* = next 32
    int4 a0, a1, a2, a3, a4, a5, a6, a7, b0, b1, b2, b3, b4, b5, b6, b7;
    {
        const int4* o4 = (const int4*)obp;
        a0 = o4[0];  a1 = o4[1];  a2 = o4[2];  a3 = o4[3];
        a4 = o4[4];  a5 = o4[5];  a6 = o4[6];  a7 = o4[7];
        b0 = o4[8];  b1 = o4[9];  b2 = o4[10]; b3 = o4[11];
        b4 = o4[12]; b5 = o4[13]; b6 = o4[14]; b7 = o4[15];
    }

    v2f p[2];
    p[0] = (v2f){0.f,0.f}; p[1] = (v2f){0.f,0.f};
    float ll = 0.0f;
    v2f eb[4][2];
    int par = 0;

    // t = 0: states 0..3 live at wave0 local pos 96..99 (lane 24)
    {
        int o0 = __builtin_amdgcn_readfirstlane(a0.x);
        float4 q = *(const float4*)(ebase + o0*SPW + 4*l);
        if (wv == 0 && l == 24) {
            p[0].x = q.x * Ivec[0];   // state 0 (pos 96)
            p[0].y = q.y * Ivec[2];   // state 2 (pos 98)
            p[1].x = q.z * Ivec[1];   // state 1 (pos 97)
            p[1].y = q.w * Ivec[3];   // state 3 (pos 99)
        }
    }

    BOUNDARY();   // t=0: z0, log, renorm, (zero) halo import

    // initial emission buffers for steps 1..4 (ids 1,2,3,0)
    PFX(1, a0.y); PFX(2, a0.z); PFX(3, a0.w); PFX(0, a1.x);

    // windows g = 0..254: steps 32g+1 .. 32g+32, boundary after each.
    // Refill at step t targets t+4 -> obs a1.y .. b1.x = obs[32g+5 .. 32g+36].
    #pragma unroll 1
    for (int g = 0; g < 255; ++g) {
        STEPX(1, a1.y); STEPX(2, a1.z); STEPX(3, a1.w); STEPX(0, a2.x);
        STEPX(1, a2.y); STEPX(2, a2.z); STEPX(3, a2.w); STEPX(0, a3.x);
        STEPX(1, a3.y); STEPX(2, a3.z); STEPX(3, a3.w); STEPX(0, a4.x);
        STEPX(1, a4.y); STEPX(2, a4.z); STEPX(3, a4.w); STEPX(0, a5.x);
        STEPX(1, a5.y); STEPX(2, a5.z); STEPX(3, a5.w); STEPX(0, a6.x);
        STEPX(1, a6.y); STEPX(2, a6.z); STEPX(3, a6.w); STEPX(0, a7.x);
        STEPX(1, a7.y); STEPX(2, a7.z); STEPX(3, a7.w); STEPX(0, b0.x);
        STEPX(1, b0.y); STEPX(2, b0.z); STEPX(3, b0.w); STEPX(0, b1.x);
        BOUNDARY();
        a1 = b1; a2 = b2; a3 = b3; a4 = b4; a5 = b5; a6 = b6; a7 = b7;
        int off = 32*(g+2); if (off > TT-32) off = TT-32;
        const int4* o4 = (const int4*)(obp + off);
        b0 = o4[0]; b1 = o4[1]; b2 = o4[2]; b3 = o4[3];
        b4 = o4[4]; b5 = o4[5]; b6 = o4[6]; b7 = o4[7];
    }

    // final partial window: steps 8161..8191 (31 steps; 27 refill + 4 consume)
    STEPX(1, a1.y); STEPX(2, a1.z); STEPX(3, a1.w); STEPX(0, a2.x);
    STEPX(1, a2.y); STEPX(2, a2.z); STEPX(3, a2.w); STEPX(0, a3.x);
    STEPX(1, a3.y); STEPX(2, a3.z); STEPX(3, a3.w); STEPX(0, a4.x);
    STEPX(1, a4.y); STEPX(2, a4.z); STEPX(3, a4.w); STEPX(0, a5.x);
    STEPX(1, a5.y); STEPX(2, a5.z); STEPX(3, a5.w); STEPX(0, a6.x);
    STEPX(1, a6.y); STEPX(2, a6.z); STEPX(3, a6.w); STEPX(0, a7.x);
    STEPX(1, a7.y); STEPX(2, a7.z); STEPX(3, a7.w);
    STEPC(0); STEPC(1); STEPC(2); STEPC(3);

    // final z (cross-wave)
    {
        v2f t = p[0] + p[1];
        float zr = (t.x + t.y) * zmask;
        zr = dpp_add<0x111>(zr); zr = dpp_add<0x112>(zr);
        zr = dpp_add<0x114>(zr); zr = dpp_add<0x118>(zr);
        zr = dpp_add<0x142>(zr); zr = dpp_add<0x143>(zr);
        if (l == 63) box[par][wv][96] = zr;
        __syncthreads();
        float z = ((box[par][0][96] + box[par][1][96]) +
                   (box[par][2][96] + box[par][3][96]));
        ll += __logf(z);
    }
    if (tid == 0) out[b] = ll;
}

extern "C" void kernel_launch(void* const* d_in, const int* in_sizes, int n_in,
                              void* d_out, int out_size, void* d_ws, size_t ws_size,
                              hipStream_t stream)
{
    const float* x  = (const float*)d_in[0];   // inputs [32,8192,101]
    const float* ik = (const float*)d_in[1];   // init_kernel [4]
    const float* tk = (const float*)d_in[2];   // transition_kernel [1836]
    const float* ek = (const float*)d_in[3];   // emission_kernel [58656]
    float* out = (float*)d_out;

    char* ws = (char*)d_ws;
    float*  wIn2  = (float*)(ws + WIN_OFF);
    float*  Ivec  = (float*)(ws + IV_OFF);
    float*  emisP = (float*)(ws + EMIS_OFF);
    int*    obs   = (int*)(ws + OBS_OFF);

    hipLaunchKernelGGL(prep_tables, dim3(3), dim3(256), 0, stream, tk, ik, wIn2, Ivec);
    hipLaunchKernelGGL(prep_emis4, dim3((4*100*SPW + 255)/256), dim3(256), 0, stream,
                       ek, emisP);
    hipLaunchKernelGGL(extract_obs, dim3((NB*TT + 3)/4), dim3(256), 0, stream, x, obs);
    hipLaunchKernelGGL(forward, dim3(NB), dim3(256), 0, stream,
                       emisP, (const float4*)wIn2, Ivec, obs, out);
}